// Round 2
// baseline (170.370 us; speedup 1.0000x reference)
//
#include <hip/hip_runtime.h>
#include <hip/hip_bf16.h>

// SupConLoss forward, fused flash-style: never materialize the 8192x8192 logits.
// Round 2: latency-oriented restructure. 32 rows/wave (2 row-tiles), B-fragment
// reuse across 8 MFMAs, software prefetch of next column tile, atomics for
// cross-chunk combine, perfectly-balanced 2-round grid.
constexpr int B_SZ = 4096;
constexpr int N_SZ = 8192;   // B*V
constexpr int CHUNK = 256;   // columns per block (grid.y chunk)
constexpr int NTILE = CHUNK / 16;

typedef __attribute__((ext_vector_type(8))) __bf16 bf16x8;
typedef __attribute__((ext_vector_type(4))) float f32x4;

// exp(dot/T) = exp2(dot * 1/(T*ln2));  T = 0.3
#define EXP2_SCALE 4.8089834f
// -(TEMPERATURE / BASE_TEMPERATURE)
#define NEG_RATIO (-(0.3f / 0.07f))

__device__ __forceinline__ unsigned short f2bf(float f) {
    unsigned u = __float_as_uint(f);
    u += 0x7FFFu + ((u >> 16) & 1u);   // round-to-nearest-even
    return (unsigned short)(u >> 16);
}

// features [B, V, D] f32 -> Abf [N, 128] bf16 (view-major row v*B+b); also zero S/P.
__global__ __launch_bounds__(256) void prep_kernel(const float* __restrict__ feat,
                                                   unsigned short* __restrict__ Abf,
                                                   float* __restrict__ S,
                                                   float* __restrict__ P) {
    int t = blockIdx.x * 256 + threadIdx.x;  // 0 .. N*128/4-1 = 262143
    if (t < N_SZ) { S[t] = 0.f; P[t] = 0.f; }
    int n = t >> 5;                          // output row
    int q = (t & 31) << 2;                   // d offset (x4 vectorized)
    int b = n & (B_SZ - 1);
    int v = n >> 12;                         // n / B_SZ
    const float4 f = *reinterpret_cast<const float4*>(feat + (((size_t)b * 2 + v) << 7) + q);
    ushort4 o;
    o.x = f2bf(f.x); o.y = f2bf(f.y); o.z = f2bf(f.z); o.w = f2bf(f.w);
    *reinterpret_cast<ushort4*>(Abf + (((size_t)n) << 7) + q) = o;
}

// Block: 4 waves x 32 rows = 128 rows, one 256-column chunk.
// Per wave: hoisted A frags (2 row-tiles), prefetched B frags, 8 MFMA per B load,
// fused exp / label-mask epilogue (diag via wave-uniform branch), butterfly reduce,
// atomicAdd combine into S/P.
__global__ __launch_bounds__(256, 4) void gram_kernel(const unsigned short* __restrict__ Abf,
                                                      const int* __restrict__ labels,
                                                      float* __restrict__ S,
                                                      float* __restrict__ P) {
    const int tid  = threadIdx.x;
    const int wave = tid >> 6;
    const int lane = tid & 63;
    const int grp  = lane >> 4;   // 0..3  (k-group)
    const int lc   = lane & 15;   // 0..15 (col within tile / row for A-frag)
    const int waveRow = blockIdx.x * 128 + wave * 32;
    const int col0    = blockIdx.y * CHUNK;

    // A fragments: rt in {0,1}; frag g covers k = 32g + 8*grp + [0..8)
    bf16x8 a[2][4];
#pragma unroll
    for (int rt = 0; rt < 2; ++rt) {
        const unsigned short* ap = Abf + ((size_t)(waveRow + 16 * rt + lc) << 7) + grp * 8;
        a[rt][0] = *reinterpret_cast<const bf16x8*>(ap);
        a[rt][1] = *reinterpret_cast<const bf16x8*>(ap + 32);
        a[rt][2] = *reinterpret_cast<const bf16x8*>(ap + 64);
        a[rt][3] = *reinterpret_cast<const bf16x8*>(ap + 96);
    }
    // Row labels for this lane's C/D rows: row = waveRow + 16*rt + 4*grp + r
    int labR[2][4];
#pragma unroll
    for (int rt = 0; rt < 2; ++rt)
#pragma unroll
        for (int r = 0; r < 4; ++r)
            labR[rt][r] = labels[(waveRow + 16 * rt + 4 * grp + r) & (B_SZ - 1)];

    float s_acc[2][4] = {{0.f,0.f,0.f,0.f},{0.f,0.f,0.f,0.f}};
    float p_acc[2][4] = {{0.f,0.f,0.f,0.f},{0.f,0.f,0.f,0.f}};

    const unsigned short* colBase = Abf + ((size_t)(col0 + lc) << 7) + grp * 8;

    // prologue: tile 0 B-frags + column labels
    bf16x8 bc[4];
    bc[0] = *reinterpret_cast<const bf16x8*>(colBase);
    bc[1] = *reinterpret_cast<const bf16x8*>(colBase + 32);
    bc[2] = *reinterpret_cast<const bf16x8*>(colBase + 64);
    bc[3] = *reinterpret_cast<const bf16x8*>(colBase + 96);
    int labC = labels[(col0 + lc) & (B_SZ - 1)];

#pragma unroll
    for (int t = 0; t < NTILE; ++t) {
        // software prefetch of tile t+1 (overlaps MFMA + epilogue below)
        bf16x8 bn[4] = {};
        int labN = 0;
        if (t + 1 < NTILE) {
            const unsigned short* p = colBase + (size_t)(t + 1) * 16 * 128;
            bn[0] = *reinterpret_cast<const bf16x8*>(p);
            bn[1] = *reinterpret_cast<const bf16x8*>(p + 32);
            bn[2] = *reinterpret_cast<const bf16x8*>(p + 64);
            bn[3] = *reinterpret_cast<const bf16x8*>(p + 96);
            labN = labels[(col0 + 16 * (t + 1) + lc) & (B_SZ - 1)];
        }

        // two independent accumulator chains (rt=0,1), g-major interleave
        f32x4 acc0 = {0.f,0.f,0.f,0.f};
        f32x4 acc1 = {0.f,0.f,0.f,0.f};
#pragma unroll
        for (int g = 0; g < 4; ++g) {
            acc0 = __builtin_amdgcn_mfma_f32_16x16x32_bf16(a[0][g], bc[g], acc0, 0, 0, 0);
            acc1 = __builtin_amdgcn_mfma_f32_16x16x32_bf16(a[1][g], bc[g], acc1, 0, 0, 0);
        }

        const int J = col0 + 16 * t;
#pragma unroll
        for (int rt = 0; rt < 2; ++rt) {
            const f32x4 acc = rt ? acc1 : acc0;   // static select (unrolled)
            const int rowTile = waveRow + 16 * rt;
            if (rowTile == J) {   // wave-uniform: the single diagonal tile
#pragma unroll
                for (int r = 0; r < 4; ++r) {
                    const float dot = acc[r];
                    const bool dg = (lc == 4 * grp + r);
                    s_acc[rt][r] += dg ? 0.f : exp2f(dot * EXP2_SCALE);
                    p_acc[rt][r] += ((labR[rt][r] == labC) && !dg) ? dot : 0.f;
                }
            } else {
#pragma unroll
                for (int r = 0; r < 4; ++r) {
                    const float dot = acc[r];
                    s_acc[rt][r] += exp2f(dot * EXP2_SCALE);
                    p_acc[rt][r] += (labR[rt][r] == labC) ? dot : 0.f;
                }
            }
        }

#pragma unroll
        for (int g = 0; g < 4; ++g) bc[g] = bn[g];
        labC = labN;
    }

    // reduce across the 16 column-lanes of each k-group
#pragma unroll
    for (int m = 1; m < 16; m <<= 1)
#pragma unroll
        for (int rt = 0; rt < 2; ++rt)
#pragma unroll
            for (int r = 0; r < 4; ++r) {
                s_acc[rt][r] += __shfl_xor(s_acc[rt][r], m);
                p_acc[rt][r] += __shfl_xor(p_acc[rt][r], m);
            }

    if (lc == 0) {
#pragma unroll
        for (int rt = 0; rt < 2; ++rt)
#pragma unroll
            for (int r = 0; r < 4; ++r) {
                const int row = waveRow + 16 * rt + 4 * grp + r;
                atomicAdd(&S[row], s_acc[rt][r]);
                atomicAdd(&P[row], p_acc[rt][r]);
            }
    }
}

// Single block: label count, per-row loss terms, mean -> scalar.
__global__ __launch_bounds__(256) void final_kernel(const float* __restrict__ S,
                                                    const float* __restrict__ P,
                                                    const int* __restrict__ labels,
                                                    float* __restrict__ out) {
    __shared__ float redf[4];
    __shared__ int   redi[4];
    const int tid = threadIdx.x;

    int c = 0;
    for (int i = tid; i < B_SZ; i += 256) c += labels[i];
#pragma unroll
    for (int m = 1; m < 64; m <<= 1) c += __shfl_xor(c, m);
    if ((tid & 63) == 0) redi[tid >> 6] = c;
    __syncthreads();
    const int c1 = redi[0] + redi[1] + redi[2] + redi[3];

    float acc = 0.f;
    for (int i = tid; i < N_SZ; i += 256) {
        const float Sv = S[i];
        const float Pv = P[i];
        const int lab = labels[i & (B_SZ - 1)];
        const int csame = lab ? c1 : (B_SZ - c1);
        const float n = (float)(2 * csame - 1);
        const float L = logf(Sv + 1e-8f);
        acc += (Pv * (1.0f / 0.3f) - n * L) / (n + 1e-8f);
    }
#pragma unroll
    for (int m = 1; m < 64; m <<= 1) acc += __shfl_xor(acc, m);
    if ((tid & 63) == 0) redf[tid >> 6] = acc;
    __syncthreads();
    if (tid == 0) {
        const float tot = redf[0] + redf[1] + redf[2] + redf[3];
        out[0] = tot * (NEG_RATIO / (float)N_SZ);
    }
}

extern "C" void kernel_launch(void* const* d_in, const int* in_sizes, int n_in,
                              void* d_out, int out_size, void* d_ws, size_t ws_size,
                              hipStream_t stream) {
    const float* feat  = (const float*)d_in[0];
    const int* labels  = (const int*)d_in[1];
    float* out = (float*)d_out;

    unsigned short* Abf = (unsigned short*)d_ws;                       // 2 MB
    float* S = (float*)((char*)d_ws + (size_t)N_SZ * 128 * 2);         // 32 KB
    float* P = S + N_SZ;                                               // 32 KB

    prep_kernel<<<dim3(N_SZ * 128 / 4 / 256), dim3(256), 0, stream>>>(feat, Abf, S, P);
    gram_kernel<<<dim3(N_SZ / 128, N_SZ / CHUNK), dim3(256), 0, stream>>>(Abf, labels, S, P);
    final_kernel<<<dim3(1), dim3(256), 0, stream>>>(S, P, labels, out);
}

// Round 3
// 64.479 us; speedup vs baseline: 2.6422x; 2.6422x over previous
//
#include <hip/hip_runtime.h>
#include <hip/hip_bf16.h>

// SupConLoss forward, fused flash-style. Round 3:
//  - no atomics (per-chunk partials; round-2's 20x HBM blowup was the cross-XCD atomics)
//  - B tiles staged to LDS once per block via global_load_lds(16B), double-buffered,
//    shared by 4 waves; XOR-swizzled source + swizzled ds_read (rule #21)
//  - A-side pre-scaled by 1/(T*ln2) so epilogue = exp2 + add + fma per element
//  - P via sign trick: P = 0.5*(p_all + sigma_row * p_net), diag excluded in its subtile
constexpr int B_SZ  = 4096;
constexpr int N_SZ  = 8192;            // B*V
constexpr int CHUNK = 1024;            // cols per block
constexpr int TILE  = 64;              // cols per LDS stage tile
constexpr int NT    = CHUNK / TILE;    // 16
constexpr int NCH   = N_SZ / CHUNK;    // 8

typedef __attribute__((ext_vector_type(8))) __bf16 bf16x8;
typedef __attribute__((ext_vector_type(4))) float f32x4;

#define CSC   4.80898346963f   // 1/(0.3*ln2): pre-scale so exp2(acc) = exp(dot/T)
#define LN2F  0.69314718056f
#define NEG_RATIO (-(0.3f / 0.07f))

__device__ __forceinline__ unsigned short f2bf(float f) {
    unsigned u = __float_as_uint(f);
    u += 0x7FFFu + ((u >> 16) & 1u);
    return (unsigned short)(u >> 16);
}

__device__ __forceinline__ void gl_lds16(const unsigned short* g, unsigned short* l) {
    __builtin_amdgcn_global_load_lds(
        (const __attribute__((address_space(1))) unsigned int*)g,
        (__attribute__((address_space(3))) unsigned int*)l, 16, 0, 0);
}

// feat [B,V,128] f32 -> Abf [N,128] bf16 (unit), Asc [N,128] bf16 (x CSC), sigF [N] = +-1
__global__ __launch_bounds__(256) void prep_kernel(const float* __restrict__ feat,
                                                   const int* __restrict__ labels,
                                                   unsigned short* __restrict__ Abf,
                                                   unsigned short* __restrict__ Asc,
                                                   float* __restrict__ sigF) {
    int t = blockIdx.x * 256 + threadIdx.x;  // 0 .. 262143
    int n = t >> 5;
    int q = (t & 31) << 2;
    int b = n & (B_SZ - 1);
    int v = n >> 12;
    const float4 f = *reinterpret_cast<const float4*>(feat + (((size_t)b * 2 + v) << 7) + q);
    ushort4 o, s;
    o.x = f2bf(f.x); o.y = f2bf(f.y); o.z = f2bf(f.z); o.w = f2bf(f.w);
    s.x = f2bf(f.x * CSC); s.y = f2bf(f.y * CSC); s.z = f2bf(f.z * CSC); s.w = f2bf(f.w * CSC);
    *reinterpret_cast<ushort4*>(Abf + (((size_t)n) << 7) + q) = o;
    *reinterpret_cast<ushort4*>(Asc + (((size_t)n) << 7) + q) = s;
    if (t < N_SZ) sigF[t] = labels[t & (B_SZ - 1)] ? 1.0f : -1.0f;
}

// Block: 4 waves x 32 rows = 128 rows, one 1024-col chunk, LDS-staged 64-col tiles.
__global__ __launch_bounds__(256, 2) void gram_kernel(const unsigned short* __restrict__ Abf,
                                                      const unsigned short* __restrict__ Asc,
                                                      const float* __restrict__ sigF,
                                                      float* __restrict__ S_part,
                                                      float* __restrict__ P_part) {
    __shared__ __align__(16) unsigned short tileBuf[2][TILE * 128];  // 2 x 16 KB
    __shared__ float sigC[CHUNK];                                    // 4 KB

    const int tid  = threadIdx.x;
    const int wave = tid >> 6;
    const int lane = tid & 63;
    const int grp  = lane >> 4;
    const int lc   = lane & 15;
    const int waveRow = blockIdx.x * 128 + wave * 32;
    const int col0    = blockIdx.y * CHUNK;

    for (int i = tid; i < CHUNK; i += 256) sigC[i] = sigF[col0 + i];

    // A fragments from the pre-scaled copy
    bf16x8 a[2][4];
#pragma unroll
    for (int rt = 0; rt < 2; ++rt) {
        const unsigned short* ap = Asc + ((size_t)(waveRow + 16 * rt + lc) << 7) + grp * 8;
        a[rt][0] = *reinterpret_cast<const bf16x8*>(ap);
        a[rt][1] = *reinterpret_cast<const bf16x8*>(ap + 32);
        a[rt][2] = *reinterpret_cast<const bf16x8*>(ap + 64);
        a[rt][3] = *reinterpret_cast<const bf16x8*>(ap + 96);
    }
    float sR[2][4];
#pragma unroll
    for (int rt = 0; rt < 2; ++rt)
#pragma unroll
        for (int r = 0; r < 4; ++r)
            sR[rt][r] = sigF[waveRow + 16 * rt + 4 * grp + r];

    float s_acc[2][4] = {{0,0,0,0},{0,0,0,0}};
    float pa[2][4]    = {{0,0,0,0},{0,0,0,0}};
    float pn[2][4]    = {{0,0,0,0},{0,0,0,0}};

    // stage tile t into buf: LDS slot s=(r,c) holds global 16B-chunk (c ^ (r&7)) of tile-row r
    auto stage = [&](int buf, int t) {
        const unsigned short* gbase = Abf + ((size_t)(col0 + t * TILE) << 7);
#pragma unroll
        for (int k = 0; k < 4; ++k) {
            const int s = tid + 256 * k;           // 0..1023 16B slots
            const int r = s >> 4, c = s & 15;
            const int srcSlot = (r << 4) + (c ^ (r & 7));
            gl_lds16(gbase + srcSlot * 8, &tileBuf[buf][s * 8]);
        }
    };

    stage(0, 0);
    __syncthreads();

    for (int t = 0; t < NT; ++t) {
        const int cur = t & 1;
        if (t + 1 < NT) stage(cur ^ 1, t + 1);

        const unsigned short* tb = tileBuf[cur];
#pragma unroll
        for (int ct = 0; ct < 4; ++ct) {
            const int tc = 16 * ct + lc;                 // tile-local column
            const unsigned short* rowp = tb + tc * 128;
            bf16x8 bfr[4];
#pragma unroll
            for (int g = 0; g < 4; ++g) {
                const int ch = (4 * g + grp) ^ (tc & 7); // un-swizzle on read
                bfr[g] = *reinterpret_cast<const bf16x8*>(rowp + ch * 8);
            }
            f32x4 acc0 = {0,0,0,0}, acc1 = {0,0,0,0};
#pragma unroll
            for (int g = 0; g < 4; ++g) {
                acc0 = __builtin_amdgcn_mfma_f32_16x16x32_bf16(a[0][g], bfr[g], acc0, 0, 0, 0);
                acc1 = __builtin_amdgcn_mfma_f32_16x16x32_bf16(a[1][g], bfr[g], acc1, 0, 0, 0);
            }

            const float sC = sigC[t * TILE + 16 * ct + lc];
            const int colTile = col0 + t * TILE + 16 * ct;
#pragma unroll
            for (int rt = 0; rt < 2; ++rt) {
                const f32x4 acc = rt ? acc1 : acc0;
                if (colTile == waveRow + 16 * rt) {      // wave-uniform diag subtile
#pragma unroll
                    for (int r = 0; r < 4; ++r) {
                        const bool dg = (lc == 4 * grp + r);
                        const float d = acc[r];
                        s_acc[rt][r] += dg ? 0.f : __builtin_exp2f(d);
                        pa[rt][r]    += dg ? 0.f : d;
                        pn[rt][r]    += dg ? 0.f : sC * d;
                    }
                } else {
#pragma unroll
                    for (int r = 0; r < 4; ++r) {
                        const float d = acc[r];
                        s_acc[rt][r] += __builtin_exp2f(d);
                        pa[rt][r]    += d;
                        pn[rt][r]     = fmaf(sC, d, pn[rt][r]);
                    }
                }
            }
        }
        __syncthreads();
    }

    // reduce across the 16 column-lanes of each k-group
#pragma unroll
    for (int m = 1; m < 16; m <<= 1)
#pragma unroll
        for (int rt = 0; rt < 2; ++rt)
#pragma unroll
            for (int r = 0; r < 4; ++r) {
                s_acc[rt][r] += __shfl_xor(s_acc[rt][r], m);
                pa[rt][r]    += __shfl_xor(pa[rt][r], m);
                pn[rt][r]    += __shfl_xor(pn[rt][r], m);
            }

    if (lc == 0) {
        const size_t base = (size_t)blockIdx.y * N_SZ;
#pragma unroll
        for (int rt = 0; rt < 2; ++rt)
#pragma unroll
            for (int r = 0; r < 4; ++r) {
                const int row = waveRow + 16 * rt + 4 * grp + r;
                S_part[base + row] = s_acc[rt][r];
                P_part[base + row] = 0.5f * (pa[rt][r] + sR[rt][r] * pn[rt][r]);
            }
    }
}

// One block: label count, combine 8 partials/row, loss terms, mean -> scalar.
__global__ __launch_bounds__(256) void final_kernel(const float* __restrict__ S_part,
                                                    const float* __restrict__ P_part,
                                                    const int* __restrict__ labels,
                                                    float* __restrict__ out) {
    __shared__ float redf[4];
    __shared__ int   redi[4];
    const int tid = threadIdx.x;

    int c = 0;
    for (int i = tid; i < B_SZ; i += 256) c += labels[i];
#pragma unroll
    for (int m = 1; m < 64; m <<= 1) c += __shfl_xor(c, m);
    if ((tid & 63) == 0) redi[tid >> 6] = c;
    __syncthreads();
    const int c1 = redi[0] + redi[1] + redi[2] + redi[3];

    float acc = 0.f;
    for (int i = tid; i < N_SZ; i += 256) {
        float S = 0.f, P = 0.f;
#pragma unroll
        for (int k = 0; k < NCH; ++k) {
            S += S_part[(size_t)k * N_SZ + i];
            P += P_part[(size_t)k * N_SZ + i];
        }
        const int lab = labels[i & (B_SZ - 1)];
        const int cs  = lab ? c1 : (B_SZ - c1);
        const float n = (float)(2 * cs - 1);
        // P holds sum(mask * dot * CSC); dot/T = dotCSC * ln2
        acc += (P * LN2F - n * logf(S + 1e-8f)) / (n + 1e-8f);
    }
#pragma unroll
    for (int m = 1; m < 64; m <<= 1) acc += __shfl_xor(acc, m);
    if ((tid & 63) == 0) redf[tid >> 6] = acc;
    __syncthreads();
    if (tid == 0) {
        const float tot = redf[0] + redf[1] + redf[2] + redf[3];
        out[0] = tot * (NEG_RATIO / (float)N_SZ);
    }
}

extern "C" void kernel_launch(void* const* d_in, const int* in_sizes, int n_in,
                              void* d_out, int out_size, void* d_ws, size_t ws_size,
                              hipStream_t stream) {
    const float* feat  = (const float*)d_in[0];
    const int* labels  = (const int*)d_in[1];
    float* out = (float*)d_out;

    char* ws = (char*)d_ws;
    unsigned short* Abf = (unsigned short*)ws;                         // 2 MB
    unsigned short* Asc = (unsigned short*)(ws + (size_t)2 * 1024 * 1024);   // 2 MB
    float* sigF   = (float*)(ws + (size_t)4 * 1024 * 1024);            // 32 KB
    float* S_part = (float*)(ws + (size_t)4 * 1024 * 1024 + 32 * 1024);      // 256 KB
    float* P_part = S_part + (size_t)NCH * N_SZ;                       // 256 KB

    prep_kernel<<<dim3(N_SZ * 128 / 4 / 256), dim3(256), 0, stream>>>(feat, labels, Abf, Asc, sigF);
    gram_kernel<<<dim3(N_SZ / 128, NCH), dim3(256), 0, stream>>>(Abf, Asc, sigF, S_part, P_part);
    final_kernel<<<dim3(1), dim3(256), 0, stream>>>(S_part, P_part, labels, out);
}